// Round 3
// baseline (165.535 us; speedup 1.0000x reference)
//
#include <hip/hip_runtime.h>

// DDLG autoencoder, fully fused, batch-tile 4, ALL-fp16 packed compute.
//   out[b][o] = sum_f prob[o][f] * op_f(x[b][idx[o][0..7]])
// R1: divide-free Einstein reductions via homomorphisms:
//     ein-product = 2D/(N+D),  D=prod(f), N=prod(2-f)
//     ein-sum     = (N-D)/(N+D), N=prod(1+f), D=prod(1-f)
// R5: 48 KB LDS, 1024-thr blocks, 2 blocks/CU; conflict-free staging.
// R7: idx pre-scale folded into addressing; prep_k is probs-only.
// R8: combined-denominator finale (one rcp per gate-half over s1*s2; range
//     proof: s1*s2 <= 2.25^8 + 257 ~ 914 < 65504, numerators <= 912).
// R9 (this round): chain+finale rewritten in EXPLICIT 2-wide _Float16
//     vectors (h2 = native v_pk_*_f16 width). Counter evidence: VALU issue
//     is ~2.1x the packed-ideal inst count -- consistent with hipcc
//     scalarizing the 4-wide h4 elementwise ops. 2-wide ops have a
//     guaranteed 1:1 pk lowering. Rows load as uint2 -> bitcast to 2x h2.
//     Everything else (pairing, layers, LDS overlays, barriers) unchanged:
//       x @ [0,16384) | h0 @ [16384,24576) | h1 @ [0,4096) | h2 @ [16384,24576)

#define BATCH 4096

typedef _Float16 h2 __attribute__((ext_vector_type(2)));
typedef _Float16 h4 __attribute__((ext_vector_type(4)));

__device__ __forceinline__ float fastrcp(float x) { return __builtin_amdgcn_rcpf(x); }
__device__ __forceinline__ _Float16 hrcp(_Float16 x) {
#if __has_builtin(__builtin_amdgcn_rcph)
    return __builtin_amdgcn_rcph(x);
#else
    return (_Float16)__builtin_amdgcn_rcpf((float)x);
#endif
}

// ---------------- prep: fp16 prob table only ----------------
// probsH: [0,2048) L0 | [2048,3072) L1 | [3072,5120) L2 | [5120,9216) L3
__global__ __launch_bounds__(256) void prep_k(const float* __restrict__ w0,
                                              const float* __restrict__ w1,
                                              const float* __restrict__ w2,
                                              const float* __restrict__ w3,
                                              const int* __restrict__ is_train,
                                              h4* __restrict__ probsH) {
    const int g = blockIdx.x * 256 + threadIdx.x;   // grid 36 -> 9216 exact
    const float* w; int o;
    if (g < 2048)      { w = w0; o = g; }
    else if (g < 3072) { w = w1; o = g - 2048; }
    else if (g < 5120) { w = w2; o = g - 3072; }
    else               { w = w3; o = g - 5120; }
    float wv[4];
#pragma unroll
    for (int c = 0; c < 4; ++c) wv[c] = w[(o << 2) + c];
    float p[4];
    if (*is_train) {
        float m = fmaxf(fmaxf(wv[0], wv[1]), fmaxf(wv[2], wv[3]));
        float s = 0.0f;
#pragma unroll
        for (int c = 0; c < 4; ++c) { p[c] = __expf(wv[c] - m); s += p[c]; }
        float inv = fastrcp(s);
#pragma unroll
        for (int c = 0; c < 4; ++c) p[c] *= inv;
    } else {
        int a = 0; float best = wv[0];
#pragma unroll
        for (int c = 1; c < 4; ++c) if (wv[c] > best) { best = wv[c]; a = c; }
#pragma unroll
        for (int c = 0; c < 4; ++c) p[c] = (c == a) ? 1.0f : 0.0f;
    }
    probsH[g] = h4{(_Float16)p[0], (_Float16)p[1], (_Float16)p[2], (_Float16)p[3]};
}

// ---------------- one LDS row = 4 fp16 (batch lanes 0..3) as 2x h2 ----------------
struct Raw { h2 lo, hi; };

__device__ __forceinline__ Raw row_at(const uint2* __restrict__ rows, int i) {
    const uint2 v = rows[i];                 // one ds_read_b64
    Raw r;
    r.lo = __builtin_bit_cast(h2, v.x);
    r.hi = __builtin_bit_cast(h2, v.y);
    return r;
}
__device__ __forceinline__ h2 splat2(_Float16 s) { h2 v = {s, s}; return v; }

// ---------------- chain state: 6 parallel reductions x 2 halves ----------------
struct Chain { h2 mn0, mn1, mx0, mx1, De0, De1, Ne0, Ne1, Nc0, Nc1, Dc0, Dc1; };

__device__ __forceinline__ void cinit(Chain& C, Raw v) {
    const h2 one = splat2((_Float16)1.0f), two = splat2((_Float16)2.0f);
    C.mn0 = v.lo; C.mx0 = v.lo; C.De0 = v.lo;
    C.Ne0 = two - v.lo; C.Nc0 = one + v.lo; C.Dc0 = one - v.lo;
    C.mn1 = v.hi; C.mx1 = v.hi; C.De1 = v.hi;
    C.Ne1 = two - v.hi; C.Nc1 = one + v.hi; C.Dc1 = one - v.hi;
}
__device__ __forceinline__ void cstep(Chain& C, Raw v) {
    const h2 two = splat2((_Float16)2.0f);
    C.mn0 = __builtin_elementwise_min(C.mn0, v.lo);
    C.mn1 = __builtin_elementwise_min(C.mn1, v.hi);
    C.mx0 = __builtin_elementwise_max(C.mx0, v.lo);
    C.mx1 = __builtin_elementwise_max(C.mx1, v.hi);
    C.De0 *= v.lo;            C.De1 *= v.hi;
    C.Ne0 *= (two - v.lo);    C.Ne1 *= (two - v.hi);
    C.Nc0 += C.Nc0 * v.lo;    C.Nc1 += C.Nc1 * v.hi;   // pk_fma: Nc *= (1+v)
    C.Dc0 -= C.Dc0 * v.lo;    C.Dc1 -= C.Dc1 * v.hi;   // pk_fma: Dc *= (1-v)
}
// combined-denominator finale: one rcp per half serves both ein and coe.
__device__ __forceinline__ Raw finale(const Chain& C, h4 P) {
    h2 s10 = C.Ne0 + C.De0, s11 = C.Ne1 + C.De1;   // [1, 257]
    h2 s20 = C.Nc0 + C.Dc0, s21 = C.Nc1 + C.Dc1;   // [1, 257]
    h2 d10 = C.Nc0 - C.Dc0, d11 = C.Nc1 - C.Dc1;   // [0, 256]
    h2 ss0 = s10 * s20,     ss1 = s11 * s21;       // <= ~914: fp16-safe
    h2 r0 = {hrcp(ss0[0]), hrcp(ss0[1])};
    h2 r1 = {hrcp(ss1[0]), hrcp(ss1[1])};
    h2 t10 = (C.De0 + C.De0) * s20, t11 = (C.De1 + C.De1) * s21;  // <= 514
    h2 t20 = d10 * s10,             t21 = d11 * s11;              // <= 912
    const h2 P0 = splat2(P[0]), P1 = splat2(P[1]);
    const h2 P2 = splat2(P[2]), P3 = splat2(P[3]);
    h2 num0 = P2 * t10 + P3 * t20;
    h2 num1 = P2 * t11 + P3 * t21;
    Raw res;
    res.lo = P0 * C.mn0 + P1 * C.mx0 + num0 * r0;
    res.hi = P0 * C.mn1 + P1 * C.mx1 + num1 * r1;
    return res;
}

// ---------------- single gate (L1) ----------------
__device__ __forceinline__ Raw gate1(const uint2* __restrict__ rows,
                                     const int4* __restrict__ idx,
                                     const h4* __restrict__ probs, int o) {
    const int4 i0 = idx[o * 2], i1 = idx[o * 2 + 1];
    const h4 P = probs[o];
    Raw A[8];
    A[0] = row_at(rows, i0.x); A[1] = row_at(rows, i0.y);
    A[2] = row_at(rows, i0.z); A[3] = row_at(rows, i0.w);
    A[4] = row_at(rows, i1.x); A[5] = row_at(rows, i1.y);
    A[6] = row_at(rows, i1.z); A[7] = row_at(rows, i1.w);
    Chain C; cinit(C, A[0]);
#pragma unroll
    for (int c = 1; c < 8; ++c) cstep(C, A[c]);
    return finale(C, P);
}

// ---------------- paired gates (adjacent outputs o0, o0+1) ----------------
__device__ __forceinline__ void gate2(const uint2* __restrict__ rows,
                                      const int4* __restrict__ idx,
                                      const h4* __restrict__ probs,
                                      int o0, Raw& ra, Raw& rb) {
    const int4 a0 = idx[o0 * 2],     a1 = idx[o0 * 2 + 1];
    const int4 b0 = idx[o0 * 2 + 2], b1 = idx[o0 * 2 + 3];
    const h4 PA = probs[o0], PB = probs[o0 + 1];
    Raw A[8], B[8];
    A[0] = row_at(rows, a0.x); A[1] = row_at(rows, a0.y);
    A[2] = row_at(rows, a0.z); A[3] = row_at(rows, a0.w);
    A[4] = row_at(rows, a1.x); A[5] = row_at(rows, a1.y);
    A[6] = row_at(rows, a1.z); A[7] = row_at(rows, a1.w);
    B[0] = row_at(rows, b0.x); B[1] = row_at(rows, b0.y);
    B[2] = row_at(rows, b0.z); B[3] = row_at(rows, b0.w);
    B[4] = row_at(rows, b1.x); B[5] = row_at(rows, b1.y);
    B[6] = row_at(rows, b1.z); B[7] = row_at(rows, b1.w);
    Chain CA, CB;
    cinit(CA, A[0]);
    cinit(CB, B[0]);
#pragma unroll
    for (int c = 1; c < 8; ++c) {
        cstep(CA, A[c]);
        cstep(CB, B[c]);
    }
    ra = finale(CA, PA);
    rb = finale(CB, PB);
}

__device__ __forceinline__ uint2 raw_bits(Raw r) {
    return uint2{__builtin_bit_cast(unsigned, r.lo), __builtin_bit_cast(unsigned, r.hi)};
}

// ---------------- the fused network ----------------
// grid = 1024 (one block per 4-batch tile), block = 1024, 2 blocks/CU
__global__ __launch_bounds__(1024, 8) void ddlg_fused(const float* __restrict__ x,
                                                      const h4* __restrict__ probsH,
                                                      const int4* __restrict__ idx0,
                                                      const int4* __restrict__ idx1,
                                                      const int4* __restrict__ idx2,
                                                      const int4* __restrict__ idx3,
                                                      float* __restrict__ out) {
    __shared__ __align__(16) _Float16 lds[24576];   // 48 KB
    const int t  = threadIdx.x;
    const int b0 = blockIdx.x << 2;

    const uint2* xl  = (const uint2*)lds;            // rows [0,4096)
    const uint2* h0v = (const uint2*)(lds + 16384);  // rows [0,2048)
    const uint2* h1v = (const uint2*)lds;            // rows [0,1024) (over dead x)
    const uint2* h2v = (const uint2*)(lds + 16384);  // rows [0,2048) (over dead h0)

    // ---- stage x columns: thread owns j; 4 coalesced scalar loads -> b64 row ----
#pragma unroll
    for (int c = 0; c < 4; ++c) {
        const int j = (c << 10) + t;
        const float v0 = x[(size_t)(b0 + 0) * 4096 + j];
        const float v1 = x[(size_t)(b0 + 1) * 4096 + j];
        const float v2 = x[(size_t)(b0 + 2) * 4096 + j];
        const float v3 = x[(size_t)(b0 + 3) * 4096 + j];
        h2 a = {(_Float16)v0, (_Float16)v1};
        h2 b = {(_Float16)v2, (_Float16)v3};
        uint2 hv = {__builtin_bit_cast(unsigned, a), __builtin_bit_cast(unsigned, b)};
        *(uint2*)(lds + (j << 2)) = hv;  // stride-1 ds_write_b64: conflict-free
    }
    __syncthreads();

    // ---- L0: 4096 -> 2048, thread owns o = 2t, 2t+1 ----
    {
        Raw ra, rb;
        gate2(xl, idx0, probsH, 2 * t, ra, rb);
        uint2 ua = raw_bits(ra), ub = raw_bits(rb);
        *(uint4*)(lds + 16384 + (t << 3)) = uint4{ua.x, ua.y, ub.x, ub.y};  // rows 2t,2t+1
    }
    __syncthreads();

    // ---- L1: 2048 -> 1024, thread owns o = t ----
    {
        Raw r = gate1(h0v, idx1, probsH + 2048, t);
        *(uint2*)(lds + (t << 2)) = raw_bits(r);
    }
    __syncthreads();

    // ---- L2: 1024 -> 2048, thread owns o = 2t, 2t+1 ----
    {
        Raw ra, rb;
        gate2(h1v, idx2, probsH + 3072, 2 * t, ra, rb);
        uint2 ua = raw_bits(ra), ub = raw_bits(rb);
        *(uint4*)(lds + 16384 + (t << 3)) = uint4{ua.x, ua.y, ub.x, ub.y};
    }
    __syncthreads();

    // ---- L3: 2048 -> 4096, thread owns o = 4t..4t+3; float4 stores ----
    {
        Raw r0, r1, r2, r3;
        gate2(h2v, idx3, probsH + 5120, 4 * t,     r0, r1);
        gate2(h2v, idx3, probsH + 5120, 4 * t + 2, r2, r3);
        // batch lane b: lo holds lanes 0,1; hi holds lanes 2,3
        float4 o4;
        o4 = make_float4((float)r0.lo[0], (float)r1.lo[0], (float)r2.lo[0], (float)r3.lo[0]);
        *(float4*)(out + (size_t)(b0 + 0) * 4096 + (t << 2)) = o4;
        o4 = make_float4((float)r0.lo[1], (float)r1.lo[1], (float)r2.lo[1], (float)r3.lo[1]);
        *(float4*)(out + (size_t)(b0 + 1) * 4096 + (t << 2)) = o4;
        o4 = make_float4((float)r0.hi[0], (float)r1.hi[0], (float)r2.hi[0], (float)r3.hi[0]);
        *(float4*)(out + (size_t)(b0 + 2) * 4096 + (t << 2)) = o4;
        o4 = make_float4((float)r0.hi[1], (float)r1.hi[1], (float)r2.hi[1], (float)r3.hi[1]);
        *(float4*)(out + (size_t)(b0 + 3) * 4096 + (t << 2)) = o4;
    }
}

extern "C" void kernel_launch(void* const* d_in, const int* in_sizes, int n_in,
                              void* d_out, int out_size, void* d_ws, size_t ws_size,
                              hipStream_t stream) {
    const float* x        = (const float*)d_in[0];
    const float* w0       = (const float*)d_in[1];
    const float* w1       = (const float*)d_in[2];
    const float* w2       = (const float*)d_in[3];
    const float* w3       = (const float*)d_in[4];
    const int4*  idx0     = (const int4*)d_in[5];
    const int4*  idx1     = (const int4*)d_in[6];
    const int4*  idx2     = (const int4*)d_in[7];
    const int4*  idx3     = (const int4*)d_in[8];
    const int*   is_train = (const int*)d_in[9];
    float*       out      = (float*)d_out;

    // ws: probsH 9216*8B = 72 KB @0
    h4* probsH = (h4*)d_ws;

    prep_k<<<36, 256, 0, stream>>>(w0, w1, w2, w3, is_train, probsH);
    ddlg_fused<<<1024, 1024, 0, stream>>>(x, probsH, idx0, idx1, idx2, idx3, out);
}